// Round 4
// baseline (709.956 us; speedup 1.0000x reference)
//
#include <hip/hip_runtime.h>

#define N_BINS 15
#define GRID_MAIN 2048
#define BLOCK 256
#define ROWS 4   // rows per 16-lane group per tile

typedef float f32x4 __attribute__((ext_vector_type(4)));

// C = 128 floats = 512 B/row. A 16-lane group owns a row: lane `sub` holds
// cols [4*sub..4*sub+3] and [64+4*sub..64+4*sub+3] via two coalesced 16B loads.
// Reduction trees are 4 steps (16 lanes); each wave shuffle serves 4 rows.
// Tiles are double-buffered (named A/B, all-static indices) so each wave keeps
// 8 x 16B loads in flight while computing the previous tile.

struct Tile {
    f32x4 a[ROWS];
    f32x4 b[ROWS];
    int   lab[ROWS];
};

__device__ __forceinline__ void stage(Tile& t, const float* __restrict__ logits,
                                      const int* __restrict__ labels, int base, int sub) {
    #pragma unroll
    for (int j = 0; j < ROWS; ++j) {
        const f32x4* rp = (const f32x4*)(logits + (size_t)(base + j) * 128);
        t.a[j]   = __builtin_nontemporal_load(rp + sub);
        t.b[j]   = __builtin_nontemporal_load(rp + 16 + sub);
        t.lab[j] = labels[base + j];
    }
}

__global__ __launch_bounds__(BLOCK, 4) void ece_main(const float* __restrict__ logits,
                                                     const int* __restrict__ labels,
                                                     float* __restrict__ partial, // [3*N_BINS * nBlocks]
                                                     int N, int nBlocks) {
    __shared__ float s_acc[3 * N_BINS];
    const int tid = threadIdx.x;
    if (tid < 3 * N_BINS) s_acc[tid] = 0.f;
    __syncthreads();

    const int grp = tid >> 4;   // group id in block: 0..15
    const int sub = tid & 15;   // lane within 16-lane group

    auto processRow = [&](const f32x4 a, const f32x4 b, int lab) {
        // local max + first-index argmax over this lane's 8 elements
        const int i0 = sub * 4, i1 = 64 + sub * 4;
        float m = a[0]; int mi = i0;
        if (a[1] > m) { m = a[1]; mi = i0 + 1; }
        if (a[2] > m) { m = a[2]; mi = i0 + 2; }
        if (a[3] > m) { m = a[3]; mi = i0 + 3; }
        if (b[0] > m) { m = b[0]; mi = i1; }
        if (b[1] > m) { m = b[1]; mi = i1 + 1; }
        if (b[2] > m) { m = b[2]; mi = i1 + 2; }
        if (b[3] > m) { m = b[3]; mi = i1 + 3; }
        #pragma unroll
        for (int off = 8; off > 0; off >>= 1) {   // stays within the 16-lane group
            float om = __shfl_xor(m, off);
            int   oi = __shfl_xor(mi, off);
            if (om > m || (om == m && oi < mi)) { m = om; mi = oi; }
        }
        float s = __expf(a[0] - m) + __expf(a[1] - m) + __expf(a[2] - m) + __expf(a[3] - m)
                + __expf(b[0] - m) + __expf(b[1] - m) + __expf(b[2] - m) + __expf(b[3] - m);
        #pragma unroll
        for (int off = 8; off > 0; off >>= 1)
            s += __shfl_xor(s, off);
        if (sub == 0) {
            const float conf = 1.0f / s;           // exp(m-m)/sum = max prob
            int bin = (int)ceilf(conf * (float)N_BINS) - 1;
            bin = min(max(bin, 0), N_BINS - 1);
            const float acc = (mi == lab) ? 1.0f : 0.0f;
            atomicAdd(&s_acc[bin],              1.0f);
            atomicAdd(&s_acc[N_BINS + bin],     conf);
            atomicAdd(&s_acc[2 * N_BINS + bin], acc);
        }
    };

    auto computeTile = [&](const Tile& t) {
        #pragma unroll
        for (int j = 0; j < ROWS; ++j)
            processRow(t.a[j], t.b[j], t.lab[j]);
    };

    const int rowsPerTile = (BLOCK >> 4) * ROWS;   // 64 rows per block-tile
    const int nFullTiles  = N / rowsPerTile;
    const int grpOff      = grp * ROWS;

    // Software-pipelined loop over this block's full tiles (double-buffered).
    int t = blockIdx.x;
    if (t < nFullTiles) {
        Tile A, B;
        stage(A, logits, labels, t * rowsPerTile + grpOff, sub);
        int tn = t + nBlocks;
        bool aLive = true;
        while (tn < nFullTiles) {
            if (aLive) { stage(B, logits, labels, tn * rowsPerTile + grpOff, sub); computeTile(A); }
            else       { stage(A, logits, labels, tn * rowsPerTile + grpOff, sub); computeTile(B); }
            aLive = !aLive;
            tn += nBlocks;
        }
        if (aLive) computeTile(A); else computeTile(B);
    }

    // Tail rows (none when N % 64 == 0): owned by the block that would get the next tile.
    const int tailStart = nFullTiles * rowsPerTile;
    if (tailStart < N && blockIdx.x == (nFullTiles % nBlocks)) {
        const int base = tailStart + grpOff;
        #pragma unroll
        for (int j = 0; j < ROWS; ++j) {
            if (base + j < N) {
                const f32x4* rp = (const f32x4*)(logits + (size_t)(base + j) * 128);
                processRow(rp[sub], rp[16 + sub], labels[base + j]);
            }
        }
    }

    __syncthreads();
    // Per-block partial store: every slot written, no init / no global atomics needed.
    if (tid < 3 * N_BINS)
        partial[(size_t)tid * nBlocks + blockIdx.x] = s_acc[tid];
}

__global__ __launch_bounds__(1024) void ece_final(const float* __restrict__ partial,
                                                  float* __restrict__ out,
                                                  int nBlocks, float invN) {
    __shared__ float red[3 * N_BINS];
    const int tid = threadIdx.x;
    const int w = tid >> 6, lane = tid & 63;
    for (int s = w; s < 3 * N_BINS; s += 16) {     // wave w reduces slots w, w+16, w+32
        float sum = 0.f;
        for (int i = lane; i < nBlocks; i += 64)
            sum += partial[(size_t)s * nBlocks + i];
        #pragma unroll
        for (int off = 32; off > 0; off >>= 1)
            sum += __shfl_xor(sum, off);
        if (lane == 0) red[s] = sum;
    }
    __syncthreads();
    if (tid == 0) {
        float ece = 0.f;
        #pragma unroll
        for (int b = 0; b < N_BINS; ++b) {
            if (red[b] > 0.f)
                ece += fabsf(red[N_BINS + b] - red[2 * N_BINS + b]) * invN;
        }
        out[0] = ece;
    }
}

extern "C" void kernel_launch(void* const* d_in, const int* in_sizes, int n_in,
                              void* d_out, int out_size, void* d_ws, size_t ws_size,
                              hipStream_t stream) {
    const float* logits = (const float*)d_in[0];
    const int*   labels = (const int*)d_in[1];
    float*       out    = (float*)d_out;
    float*       partial = (float*)d_ws;           // 3*N_BINS*GRID_MAIN floats = 368 KB

    const int N = in_sizes[1];                     // 1048576 rows (C fixed at 128)

    int grid = GRID_MAIN;
    const int rowsPerTile = (BLOCK >> 4) * ROWS;
    if ((size_t)grid * rowsPerTile > (size_t)N)
        grid = (N + rowsPerTile - 1) / rowsPerTile;

    ece_main<<<grid, BLOCK, 0, stream>>>(logits, labels, partial, N, grid);
    ece_final<<<1, 1024, 0, stream>>>(partial, out, grid, 1.0f / (float)N);
}

// Round 5
// 682.079 us; speedup vs baseline: 1.0409x; 1.0409x over previous
//
#include <hip/hip_runtime.h>

#define N_BINS 15
#define GRID_MAIN 2048
#define BLOCK 256
#define ROWS 4   // rows per 16-lane group per iteration

typedef float f32x4 __attribute__((ext_vector_type(4)));

// C = 128 floats = 512 B/row. A 16-lane group owns a row: lane `sub` holds
// cols [4*sub..4*sub+3] and [64+4*sub..64+4*sub+3] via two coalesced 16B loads.
// Max tree is a pure fmax tree (1 op/stage); argmax is recovered from the
// exact zeros of v-m (IEEE: x-y==0 iff x==y) with a min-index tree, which
// preserves jnp.argmax first-occurrence tie-break. Sum and index trees are
// interleaved for ILP. Single-buffered: R4's double-buffer regressed.
__global__ __launch_bounds__(BLOCK) void ece_main(const float* __restrict__ logits,
                                                  const int* __restrict__ labels,
                                                  float* __restrict__ partial, // [3*N_BINS * nBlocks]
                                                  int N, int nBlocks) {
    __shared__ float s_acc[3 * N_BINS];
    const int tid = threadIdx.x;
    if (tid < 3 * N_BINS) s_acc[tid] = 0.f;
    __syncthreads();

    const int grp = tid >> 4;   // group id in block: 0..15
    const int sub = tid & 15;   // lane within 16-lane group

    auto processRow = [&](const f32x4 a, const f32x4 b, int lab) {
        // pure max: local fmax chain + 4-stage fmax tree
        float m = fmaxf(fmaxf(fmaxf(a[0], a[1]), fmaxf(a[2], a[3])),
                        fmaxf(fmaxf(b[0], b[1]), fmaxf(b[2], b[3])));
        #pragma unroll
        for (int off = 8; off > 0; off >>= 1)
            m = fmaxf(m, __shfl_xor(m, off));

        // differences drive both the exp-sum and the argmax recovery
        const float d0 = a[0] - m, d1 = a[1] - m, d2 = a[2] - m, d3 = a[3] - m;
        const float e0 = b[0] - m, e1 = b[1] - m, e2 = b[2] - m, e3 = b[3] - m;
        float s = __expf(d0) + __expf(d1) + __expf(d2) + __expf(d3)
                + __expf(e0) + __expf(e1) + __expf(e2) + __expf(e3);

        const int i0 = sub * 4, i1 = 64 + sub * 4, BIG = 0x7fffffff;
        int mi =          (d0 == 0.f) ? i0     : BIG;
        mi = min(mi, (d1 == 0.f) ? i0 + 1 : BIG);
        mi = min(mi, (d2 == 0.f) ? i0 + 2 : BIG);
        mi = min(mi, (d3 == 0.f) ? i0 + 3 : BIG);
        mi = min(mi, (e0 == 0.f) ? i1     : BIG);
        mi = min(mi, (e1 == 0.f) ? i1 + 1 : BIG);
        mi = min(mi, (e2 == 0.f) ? i1 + 2 : BIG);
        mi = min(mi, (e3 == 0.f) ? i1 + 3 : BIG);

        #pragma unroll
        for (int off = 8; off > 0; off >>= 1) {   // two independent trees, interleaved
            mi = min(mi, __shfl_xor(mi, off));
            s += __shfl_xor(s, off);
        }

        if (sub == 0) {
            const float conf = 1.0f / s;           // exp(m-m)/sum = max prob
            int bin = (int)ceilf(conf * (float)N_BINS) - 1;
            bin = min(max(bin, 0), N_BINS - 1);
            const float acc = (mi == lab) ? 1.0f : 0.0f;
            atomicAdd(&s_acc[bin],              1.0f);
            atomicAdd(&s_acc[N_BINS + bin],     conf);
            atomicAdd(&s_acc[2 * N_BINS + bin], acc);
        }
    };

    const int rowsPerIter = (BLOCK >> 4) * ROWS;  // 64 rows per block-iteration
    const int rowStride   = nBlocks * rowsPerIter;

    for (int tile = blockIdx.x * rowsPerIter; tile < N; tile += rowStride) {
        const int base = tile + grp * ROWS;
        if (tile + rowsPerIter <= N) {
            // fast path: all rows valid -> unconditional loads, 8 in flight/lane
            f32x4 va[ROWS], vb[ROWS];
            int   lab[ROWS];
            #pragma unroll
            for (int j = 0; j < ROWS; ++j) {
                const f32x4* rp = (const f32x4*)(logits + (size_t)(base + j) * 128);
                va[j]  = __builtin_nontemporal_load(rp + sub);
                vb[j]  = __builtin_nontemporal_load(rp + 16 + sub);
                lab[j] = labels[base + j];   // prefetched off the atomic critical path
            }
            #pragma unroll
            for (int j = 0; j < ROWS; ++j)
                processRow(va[j], vb[j], lab[j]);
        } else {
            #pragma unroll
            for (int j = 0; j < ROWS; ++j) {
                if (base + j < N) {
                    const f32x4* rp = (const f32x4*)(logits + (size_t)(base + j) * 128);
                    processRow(rp[sub], rp[16 + sub], labels[base + j]);
                }
            }
        }
    }

    __syncthreads();
    // Per-block partial store: every slot written, no init / no global atomics needed.
    if (tid < 3 * N_BINS)
        partial[(size_t)tid * nBlocks + blockIdx.x] = s_acc[tid];
}

__global__ __launch_bounds__(1024) void ece_final(const float* __restrict__ partial,
                                                  float* __restrict__ out,
                                                  int nBlocks, float invN) {
    __shared__ float red[3 * N_BINS];
    const int tid = threadIdx.x;
    const int w = tid >> 6, lane = tid & 63;
    for (int s = w; s < 3 * N_BINS; s += 16) {     // wave w reduces slots w, w+16, w+32
        float sum = 0.f;
        for (int i = lane; i < nBlocks; i += 64)
            sum += partial[(size_t)s * nBlocks + i];
        #pragma unroll
        for (int off = 32; off > 0; off >>= 1)
            sum += __shfl_xor(sum, off);
        if (lane == 0) red[s] = sum;
    }
    __syncthreads();
    if (tid == 0) {
        float ece = 0.f;
        #pragma unroll
        for (int b = 0; b < N_BINS; ++b) {
            if (red[b] > 0.f)
                ece += fabsf(red[N_BINS + b] - red[2 * N_BINS + b]) * invN;
        }
        out[0] = ece;
    }
}

extern "C" void kernel_launch(void* const* d_in, const int* in_sizes, int n_in,
                              void* d_out, int out_size, void* d_ws, size_t ws_size,
                              hipStream_t stream) {
    const float* logits = (const float*)d_in[0];
    const int*   labels = (const int*)d_in[1];
    float*       out    = (float*)d_out;
    float*       partial = (float*)d_ws;           // 3*N_BINS*GRID_MAIN floats = 368 KB

    const int N = in_sizes[1];                     // 1048576 rows (C fixed at 128)

    int grid = GRID_MAIN;
    const int rowsPerIter = (BLOCK >> 4) * ROWS;
    if ((size_t)grid * rowsPerIter > (size_t)N)
        grid = (N + rowsPerIter - 1) / rowsPerIter;

    ece_main<<<grid, BLOCK, 0, stream>>>(logits, labels, partial, N, grid);
    ece_final<<<1, 1024, 0, stream>>>(partial, out, grid, 1.0f / (float)N);
}